// Round 9
// baseline (349.313 us; speedup 1.0000x reference)
//
#include <hip/hip_runtime.h>
#include <hip/hip_bf16.h>

// Problem constants
#define B_N 16384
#define A_N 32
#define U_N 64
#define S_N 2048
#define E_N 32
#define HYP_N 64
#define H_N 4
#define NREAL 288   // 256 selector-hypernet cols + 32 v-net cols
#define NPADG 320   // GEMM N padded to 320 (20 MFMA col-tiles)

// workspace byte offsets (16B-aligned)
#define WS_WT    0                         // Wt bf16 [320][2048] = 1310720 B
#define WS_MB    1310720                   // Mb bf16 [H][U][64]  = 32768 B
#define WS_PMAG  (WS_MB + 32768)
#define WS_PENT  (WS_PMAG + 65536)

// output layout (floats): head_attend [B,A] | v [B] | mag | ent [H]
#define OUT_V   (B_N * A_N)
#define OUT_MAG (OUT_V + B_N)
#define OUT_ENT (OUT_MAG + 1)

typedef __attribute__((ext_vector_type(8))) short bf16x8_t;
typedef __attribute__((ext_vector_type(4))) float floatx4_t;

#define AS1(p) ((const __attribute__((address_space(1))) void*)(p))
#define AS3(p) ((__attribute__((address_space(3))) void*)(p))

__device__ __forceinline__ unsigned short f2b(float f) {
    union { float f; unsigned u; } v; v.f = f;
    unsigned r = v.u + 0x7FFFu + ((v.u >> 16) & 1u);   // RNE
    return (unsigned short)(r >> 16);
}
__device__ __forceinline__ float b2f(unsigned x) {
    union { unsigned u; float f; } v; v.u = x << 16; return v.f;
}

// ---------------------------------------------------------------------------
// Pack: Wt bf16 [320][2048] (W^T of [sel_w1 | v_w1 | 0]) and
//       Mb bf16 [H][U][64]: M[h][u][k] = sum_e key_w[h][u][e]*sel_w2[h][k][e]
// ---------------------------------------------------------------------------
__global__ __launch_bounds__(256) void pack_w_kernel(
        const float* __restrict__ sel_w1, const float* __restrict__ v_w1,
        const float* __restrict__ sel_w2, const float* __restrict__ key_w,
        unsigned short* __restrict__ Wt, unsigned short* __restrict__ Mb) {
    int idx = blockIdx.x * 256 + threadIdx.x;
    if (idx < NPADG * S_N) {
        int n = idx >> 11;          // / 2048
        int k = idx & 2047;
        float val = 0.0f;
        if (n < 256) {
            int h = n >> 6, kk = n & 63;
            val = sel_w1[((size_t)h * S_N + k) * HYP_N + kk];
        } else if (n < NREAL) {
            val = v_w1[(size_t)k * E_N + (n - 256)];
        }
        Wt[idx] = f2b(val);
    } else if (idx < NPADG * S_N + H_N * U_N * HYP_N) {
        int j = idx - NPADG * S_N;          // [h][u][k]
        int h = j >> 12, u = (j >> 6) & 63, k = j & 63;
        const float* kw = key_w + ((size_t)h * U_N + u) * E_N;
        const float* w2 = sel_w2 + ((size_t)h * HYP_N + k) * E_N;
        float s = 0.0f;
#pragma unroll
        for (int e = 0; e < E_N; ++e) s = fmaf(kw[e], w2[e], s);
        Mb[j] = f2b(s);
    }
}

// ---------------------------------------------------------------------------
// Fused kernel v5: A-in-registers, B double-buffered, 1 barrier per chunk.
//   BM=64, BN=320, chunk K=64 (32 chunks), 512 thr (8 waves = 4M x 2N),
//   grid 256 (1 block/CU).
//   A: each wave loads its 16 private rows DIRECTLY into MFMA A-fragment
//      layout (lane: row=lane&15, k-octet=lane>>4) as fp32, cvt->bf16 in
//      regs. No LDS, no staging barrier. 2 chunks of fp32 regs in flight.
//      Wave pair (w, w+4) re-reads same rows -> L2 hit.
//   B: global_load_lds w=16 into Bsm[2] (XOR swizzle); DMA for chunk+1
//      issued at chunk start -> complete by the chunk-end barrier.
// Then bias/relu -> h1 LDS, phase T (MFMA t = h1 @ M^T), phase L (softmax).
// ---------------------------------------------------------------------------
#define FM_BM 64
#define NCHK 32
#define H1_STRIDE 312   // shorts; +28-bank step per row -> <=2-way on frag reads
#define TS_STRIDE 260   // floats

__global__ __launch_bounds__(512, 2) void fused_kernel(
        const float* __restrict__ states, const unsigned short* __restrict__ Wt,
        const float* __restrict__ sel_b1, const float* __restrict__ v_b1,
        const unsigned short* __restrict__ Mb,
        const float* __restrict__ v_w2, const float* __restrict__ v_b2,
        float* __restrict__ out, float* __restrict__ pmag, float* __restrict__ pent) {
    // pool: Bsm 2 x 40960 B | h1b 39936 B ; tsb (66560 B) aliases Bsm after K-loop
    __shared__ __align__(16) char pool[81920 + 39936];
    unsigned short* Bsm = (unsigned short*)pool;            // 2 x 20480 shorts
    unsigned short* h1b = (unsigned short*)(pool + 81920);  // [64][312]
    float*          tsb = (float*)pool;                     // [64][260] aliases Bsm

    const int t = threadIdx.x;
    const int lane = t & 63;
    const int w = t >> 6;               // 0..7
    const int m0 = blockIdx.x * FM_BM;
    const int g = w & 3;                // M-group: rows g*16..g*16+15
    const int nh = w >> 2;              // N-half: cols nh*160..+159
    const int nbase = nh * 160;

    // A fragment source: lane (row = lane&15, k-octet = lane>>4)
    const float* arow = states + (size_t)(m0 + g * 16 + (lane & 15)) * S_N
                        + ((lane >> 4) * 8);

    floatx4_t acc[10] = {};
    float4 av[2][2][2];   // [set][step][half]: fp32 A regs, 2 chunks in flight

    auto loadA = [&](int set, int chunk) {
#pragma unroll
        for (int s = 0; s < 2; ++s) {
            const float* p = arow + chunk * 64 + s * 32;
            av[set][s][0] = *(const float4*)p;
            av[set][s][1] = *(const float4*)(p + 4);
        }
    };
    auto dmaB = [&](int chunk) {
        unsigned short* dst = Bsm + (chunk & 1) * 20480;
        const int k0 = chunk * 64;
#pragma unroll
        for (int i = 0; i < 5; ++i) {
            int p = i * 512 + t, n = p >> 3, sl = p & 7;
            int cl = sl ^ (n & 7);
            __builtin_amdgcn_global_load_lds(
                AS1(Wt + (size_t)n * S_N + k0 + cl * 8),
                AS3(dst + p * 8), 16, 0, 0);
        }
    };
    auto mkfrag = [&](int set, int s) -> bf16x8_t {
        float4 x = av[set][s][0], y = av[set][s][1];
        union { unsigned u[4]; bf16x8_t v; } r;
        r.u[0] = (unsigned)f2b(x.x) | ((unsigned)f2b(x.y) << 16);
        r.u[1] = (unsigned)f2b(x.z) | ((unsigned)f2b(x.w) << 16);
        r.u[2] = (unsigned)f2b(y.x) | ((unsigned)f2b(y.y) << 16);
        r.u[3] = (unsigned)f2b(y.z) | ((unsigned)f2b(y.w) << 16);
        return r.v;
    };

    // ---- prologue: A(0),A(1) -> regs; B(0),B(1) -> LDS bufs ----
    loadA(0, 0);
    loadA(1, 1);
    dmaB(0);
    dmaB(1);
    __syncthreads();

    // ---- K-loop: 32 chunks, ONE barrier each ----
    for (int c = 0; c < NCHK; ++c) {
        const int set = c & 1;
        bf16x8_t af0 = mkfrag(set, 0);
        bf16x8_t af1 = mkfrag(set, 1);
        if (c < NCHK - 2) loadA(set, c + 2);   // deep HBM prefetch (regs free)
        if (c < NCHK - 1) dmaB(c + 1);         // into buf^1 (readers done last barrier)
        const unsigned short* Bs = Bsm + set * 20480;
#pragma unroll
        for (int s = 0; s < 2; ++s) {
            bf16x8_t af = s ? af1 : af0;
            const int cc = s * 4 + (lane >> 4);
#pragma unroll
            for (int nt = 0; nt < 10; ++nt) {
                int n = nbase + nt * 16 + (lane & 15);
                int ph = cc ^ (n & 7);
                bf16x8_t bfr = *(const bf16x8_t*)(Bs + n * 64 + ph * 8);
                acc[nt] = __builtin_amdgcn_mfma_f32_16x16x32_bf16(
                    af, bfr, acc[nt], 0, 0, 0);
            }
        }
        if (c < NCHK - 1) __syncthreads();   // DMA(c+1) had a full compute phase
    }

    // ---- bias + relu -> h1 LDS (bf16). C/D: col=lane&15, row=(lane>>4)*4+rg
    // layout per row: head h at h*72 (k 0..63), v-col j at (j>>3)*72+64+(j&7)
#pragma unroll
    for (int nt = 0; nt < 10; ++nt) {
        int n = nbase + nt * 16 + (lane & 15);
        if (n >= NREAL) continue;
        float bias = (n < 256) ? sel_b1[n] : v_b1[n - 256];
        int slot = (n < 256) ? ((n >> 6) * 72 + (n & 63))
                             : (((n - 256) >> 3) * 72 + 64 + ((n - 256) & 7));
#pragma unroll
        for (int rg = 0; rg < 4; ++rg) {
            int r = g * 16 + (lane >> 4) * 4 + rg;
            float v = acc[nt][rg] + bias;
            h1b[r * H1_STRIDE + slot] = f2b(v > 0.0f ? v : 0.0f);
        }
    }
    __syncthreads();   // h1 complete; all Bsm reads done -> tsb may alias

    // ---- phase T: wave w -> head h = w>>1, rows half rb = (w&1)*32; MFMA ----
    {
        const int h = w >> 1;
        const int rb = (w & 1) * 32;
        floatx4_t tacc[2][4] = {};
#pragma unroll
        for (int s = 0; s < 2; ++s) {
            int k0 = s * 32 + (lane >> 4) * 8;
            bf16x8_t bfr[4];
#pragma unroll
            for (int ut = 0; ut < 4; ++ut) {
                int u = ut * 16 + (lane & 15);
                bfr[ut] = *(const bf16x8_t*)(Mb + ((size_t)(h * U_N + u) * 64) + k0);
            }
#pragma unroll
            for (int mt = 0; mt < 2; ++mt) {
                bf16x8_t afr = *(const bf16x8_t*)(
                    h1b + (rb + mt * 16 + (lane & 15)) * H1_STRIDE + h * 72 + k0);
#pragma unroll
                for (int ut = 0; ut < 4; ++ut)
                    tacc[mt][ut] = __builtin_amdgcn_mfma_f32_16x16x32_bf16(
                        afr, bfr[ut], tacc[mt][ut], 0, 0, 0);
            }
        }
#pragma unroll
        for (int mt = 0; mt < 2; ++mt)
#pragma unroll
            for (int ut = 0; ut < 4; ++ut)
#pragma unroll
                for (int rg = 0; rg < 4; ++rg) {
                    int r = rb + mt * 16 + (lane >> 4) * 4 + rg;
                    int u = ut * 16 + (lane & 15);
                    tsb[r * TS_STRIDE + h * U_N + u] = tacc[mt][ut][rg];
                }
    }
    __syncthreads();

    // ---- phase L: wave w handles rows w*8 .. w*8+7 (states L3-hot) ----
    const int a = lane & 31, uh = lane >> 5;
    float4 cur[8], nxt[8];
    {
        const float* up = states + (size_t)(m0 + w * 8) * S_N + a * 64 + uh * 32;
#pragma unroll
        for (int i = 0; i < 8; ++i) cur[i] = ((const float4*)up)[i];
    }
    for (int rr = 0; rr < 8; ++rr) {
        int r = w * 8 + rr;
        int b = m0 + r;
        if (rr < 7) {
            const float* up = states + (size_t)(b + 1) * S_N + a * 64 + uh * 32;
#pragma unroll
            for (int i = 0; i < 8; ++i) nxt[i] = ((const float4*)up)[i];
        }
        float pl[4];
#pragma unroll
        for (int h = 0; h < 4; ++h) {
            const float* tp = &tsb[r * TS_STRIDE + h * U_N + uh * 32];
            float s = 0.0f;
#pragma unroll
            for (int i = 0; i < 8; ++i) {
                float4 t4 = *(const float4*)(tp + i * 4);
                s = fmaf(cur[i].x, t4.x, s);
                s = fmaf(cur[i].y, t4.y, s);
                s = fmaf(cur[i].z, t4.z, s);
                s = fmaf(cur[i].w, t4.w, s);
            }
            pl[h] = s + __shfl_xor(s, 32, 64);   // combine u-halves
        }
        float mg = pl[0]*pl[0] + pl[1]*pl[1] + pl[2]*pl[2] + pl[3]*pl[3];
#pragma unroll
        for (int o = 16; o > 0; o >>= 1) mg += __shfl_xor(mg, o, 32);
        float hatt = 0.0f;
        float entv[4];
#pragma unroll
        for (int h = 0; h < 4; ++h) {
            float x = pl[h] * 0.17677669529663687f;   // 1/sqrt(E=32)
            float m = x;
#pragma unroll
            for (int o = 16; o > 0; o >>= 1) m = fmaxf(m, __shfl_xor(m, o, 32));
            float p = expf(x - m);
            float den = p;
#pragma unroll
            for (int o = 16; o > 0; o >>= 1) den += __shfl_xor(den, o, 32);
            float wv = p / den;
            hatt += wv;
            float e = wv * logf(wv + 1e-8f);
#pragma unroll
            for (int o = 16; o > 0; o >>= 1) e += __shfl_xor(e, o, 32);
            entv[h] = e;
        }
        if (uh == 0) {
            out[(size_t)b * A_N + a] = hatt;
            float pv = b2f((unsigned)h1b[r * H1_STRIDE + (a >> 3) * 72 + 64 + (a & 7)])
                       * v_w2[a];
#pragma unroll
            for (int o = 16; o > 0; o >>= 1) pv += __shfl_xor(pv, o, 32);
            if (a == 0) {
                out[OUT_V + b] = pv + v_b2[0];
                pmag[b] = mg;
#pragma unroll
                for (int h = 0; h < 4; ++h) pent[(size_t)h * B_N + b] = entv[h];
            }
        }
#pragma unroll
        for (int i = 0; i < 8; ++i) cur[i] = nxt[i];
    }
}

// ---------------------------------------------------------------------------
// Deterministic final reduction
// ---------------------------------------------------------------------------
__global__ __launch_bounds__(256) void finalize_kernel(
        const float* __restrict__ pmag, const float* __restrict__ pent,
        float* __restrict__ out) {
    int which = blockIdx.x;   // 0..4
    const float* src = (which == 0) ? pmag : (pent + (size_t)(which - 1) * B_N);
    float s = 0.0f;
    for (int i = threadIdx.x; i < B_N; i += 256) s += src[i];
#pragma unroll
    for (int o = 32; o > 0; o >>= 1) s += __shfl_xor(s, o, 64);
    __shared__ float red[4];
    if ((threadIdx.x & 63) == 0) red[threadIdx.x >> 6] = s;
    __syncthreads();
    if (threadIdx.x == 0) {
        float tot = red[0] + red[1] + red[2] + red[3];
        if (which == 0) out[OUT_MAG] = 1e-3f * tot / (float)(B_N * A_N);
        else out[OUT_ENT + which - 1] = -tot / (float)B_N;
    }
}

// ---------------------------------------------------------------------------
extern "C" void kernel_launch(void* const* d_in, const int* in_sizes, int n_in,
                              void* d_out, int out_size, void* d_ws, size_t ws_size,
                              hipStream_t stream) {
    const float* states = (const float*)d_in[1];
    const float* sel_w1 = (const float*)d_in[2];
    const float* sel_b1 = (const float*)d_in[3];
    const float* sel_w2 = (const float*)d_in[4];
    const float* key_w  = (const float*)d_in[5];
    const float* v_w1   = (const float*)d_in[6];
    const float* v_b1   = (const float*)d_in[7];
    const float* v_w2   = (const float*)d_in[8];
    const float* v_b2   = (const float*)d_in[9];
    float* out = (float*)d_out;
    char* wsb  = (char*)d_ws;

    unsigned short* Wt  = (unsigned short*)(wsb + WS_WT);
    unsigned short* Mb  = (unsigned short*)(wsb + WS_MB);
    float* pmag         = (float*)(wsb + WS_PMAG);
    float* pent         = (float*)(wsb + WS_PENT);

    pack_w_kernel<<<dim3((NPADG * S_N + H_N * U_N * HYP_N + 255) / 256),
                    dim3(256), 0, stream>>>(sel_w1, v_w1, sel_w2, key_w, Wt, Mb);
    fused_kernel<<<dim3(B_N / FM_BM), dim3(512), 0, stream>>>(
        states, Wt, sel_b1, v_b1, Mb, v_w2, v_b2, out, pmag, pent);
    finalize_kernel<<<dim3(5), dim3(256), 0, stream>>>(pmag, pent, out);
}